// Round 7
// baseline (172.693 us; speedup 1.0000x reference)
//
#include <hip/hip_runtime.h>

#define NN 1000
#define HEADS_ 4
#define DM 128
#define EE 64000
#define NTOT 4000
#define ETOT 68000
#define CAP 48     // bucket holds ALL edges per dst: deg ~ Poisson(16)+1, P(>=48) ~ 1e-11
#define EB 34      // edge-builder blocks appended to the h-GEMM dispatch

// ---------------------------------------------------------------------------
// 64x64 GEMM tile, K=64: C[m0..+64][n0..+64] = A @ Wt^T.
// k-group swizzle g = q ^ ((r>>2)&15). acc[4][4] only across the staged
// c-loop -- liveness pattern proven spill-free (R2/R5, 60 VGPR).
// SCORE: fused GAT score epilogue (rows < 1000 only).
// ---------------------------------------------------------------------------
template <int KK, int SCORE>
__device__ void gemm64(int mi, int ni,
                       const float* __restrict__ A, const float* __restrict__ Wt,
                       float* __restrict__ C, int N,
                       const float* __restrict__ att,
                       float* __restrict__ ssrc, float* __restrict__ sdst) {
  __shared__ float As[64 * 64];
  __shared__ float Bs[64 * 64];
  int tid = threadIdx.x;
  int m0 = mi * 64, n0 = ni * 64;
  int tx = tid & 15, ty = tid >> 4;
  const float4* A4 = (const float4*)A;
  const float4* W4 = (const float4*)Wt;
  float acc[4][4] = {};

  for (int c = 0; c < KK / 64; ++c) {
    __syncthreads();
    {
      int q = tid & 15, r0 = tid >> 4;
#pragma unroll
      for (int p = 0; p < 4; ++p) {  // A: 64 rows
        int r = r0 + p * 16;
        float4 v = A4[(size_t)(m0 + r) * (KK / 4) + c * 16 + q];
        *(float4*)&As[r * 64 + ((q ^ ((r >> 2) & 15)) << 2)] = v;
      }
#pragma unroll
      for (int p = 0; p < 4; ++p) {  // B: 64 rows
        int r = r0 + p * 16;
        float4 v = W4[(size_t)(n0 + r) * (KK / 4) + c * 16 + q];
        *(float4*)&Bs[r * 64 + ((q ^ ((r >> 2) & 15)) << 2)] = v;
      }
    }
    __syncthreads();
#pragma unroll 4
    for (int q = 0; q < 16; ++q) {
      float4 a[4], b[4];
      int sa = (q ^ ty) << 2;          // (r>>2)&15 == ty for r=ty*4+i
      int sb = (q ^ tx) << 2;
#pragma unroll
      for (int i = 0; i < 4; ++i)
        a[i] = *(const float4*)&As[(ty * 4 + i) * 64 + sa];
#pragma unroll
      for (int j = 0; j < 4; ++j)
        b[j] = *(const float4*)&Bs[(tx * 4 + j) * 64 + sb];
#pragma unroll
      for (int i = 0; i < 4; ++i)
#pragma unroll
        for (int j = 0; j < 4; ++j)
          acc[i][j] += a[i].x * b[j].x + a[i].y * b[j].y
                     + a[i].z * b[j].z + a[i].w * b[j].w;
    }
  }

  int nc = n0 + tx * 4;
#pragma unroll
  for (int i = 0; i < 4; ++i) {
    int m = m0 + ty * 4 + i;
    *(float4*)&C[(size_t)m * N + nc] =
        make_float4(acc[i][0], acc[i][1], acc[i][2], acc[i][3]);
  }

  if (SCORE && m0 < NN) {  // uniform per block
    int hsel = tx >> 3;
    int h = ni * 2 + hsel;
    int kb = (tx & 7) * 4;
    float a0[4], a1[4];
#pragma unroll
    for (int j = 0; j < 4; ++j) {
      a0[j] = att[h * 64 + kb + j];
      a1[j] = att[h * 64 + 32 + kb + j];
    }
#pragma unroll
    for (int i = 0; i < 4; ++i) {
      int m = m0 + ty * 4 + i;
      float p0 = 0.f, p1 = 0.f;
#pragma unroll
      for (int j = 0; j < 4; ++j) {
        float g = acc[i][j];
        float lr = g > 0.f ? g : 0.2f * g;
        p0 += a0[j] * lr;
        p1 += a1[j] * lr;
      }
      p0 += __shfl_xor(p0, 1, 16); p1 += __shfl_xor(p1, 1, 16);
      p0 += __shfl_xor(p0, 2, 16); p1 += __shfl_xor(p1, 2, 16);
      p0 += __shfl_xor(p0, 4, 16); p1 += __shfl_xor(p1, 4, 16);
      if ((tx & 7) == 0 && m < NN) {
        ssrc[m * HEADS_ + h] = p0;
        sdst[m * HEADS_ + h] = p1;
      }
    }
  }
}

// -------- K1: blocks 0..499 = h-GEMM (250 m-tiles x 2 n-tiles) + score
//              blocks 500..499+EB = bucket build    (R5 proven)
__global__ __launch_bounds__(256) void k1_kernel(const float* __restrict__ x,
                                                 const float* __restrict__ W,
                                                 const float* __restrict__ att,
                                                 float* __restrict__ hbuf,
                                                 float* __restrict__ ssrc,
                                                 float* __restrict__ sdst,
                                                 const int* __restrict__ ei,
                                                 int* __restrict__ cnt,
                                                 int* __restrict__ elist) {
  int bid = blockIdx.x;
  if (bid < 500) {
    gemm64<64, 1>(bid >> 1, bid & 1, x, W, hbuf, 128, att, ssrc, sdst);
  } else {
    for (int e = (bid - 500) * 256 + threadIdx.x; e < ETOT; e += EB * 256) {
      int s, d;
      if (e < EE) { s = ei[e]; d = ei[EE + e]; }
      else { s = d = e - EE; }  // self loops
      int pos = atomicAdd(&cnt[d], 1);
      if (pos < CAP) elist[d * CAP + pos] = s;
    }
  }
}

// ---------------------------------------------------------------------------
// K2 (gfuse2): gather (R5-proven, per-head alpha on h) + in-block qkv GEMM
// + register MHA + out_proj.  2 dst/block, 256 threads, 2000 blocks.
// LDS 49.4 KB -> 3 blocks/CU.
// Layout (floats): srcs[96i] | exs[384] | hgatS[8][132] | qkvS[8][392] |
//                  inwS[384][20]  (overlay after B: outwS[4096] aoS[1024])
// Bank design: hgatS row pad 132 -> a-reads banks 4r (conflict-free bcast);
// inwS row pad 20 (80 B) -> cb-lanes hit 8 distinct bank-groups (free);
// qkv lane = (r=l&7, cb=l>>3), cols c = w*96+cb+8j, acc[12] per lane.
// ---------------------------------------------------------------------------
__global__ __launch_bounds__(256) void gfuse2_kernel(const int* __restrict__ cnt,
                                                     const int* __restrict__ elist,
                                                     const float* __restrict__ ssrc,
                                                     const float* __restrict__ sdst,
                                                     const float* __restrict__ hbuf,
                                                     const float* __restrict__ inw,
                                                     const float* __restrict__ inb,
                                                     const float* __restrict__ outw,
                                                     const float* __restrict__ outb,
                                                     const float* __restrict__ bias,
                                                     float* __restrict__ out) {
  __shared__ float smem[12352];
  int*   srcs  = (int*)smem;          // [2][CAP]
  float* exs   = smem + 96;           // [2][CAP][4]
  float* hgatS = smem + 480;          // [8][132]
  float* qkvS  = smem + 1536;         // [8][392]
  float* inwS  = smem + 4672;         // [384][20]   (phase B)
  float* outwS = smem + 4672;         // [4096] swz  (phase D overlay)
  float* aoS   = smem + 8768;         // [2][4][128] (phase C overlay)

  int tid = threadIdx.x;
  int li = tid >> 7;
  int t = tid & 127;
  int d = blockIdx.x * 2 + li;
  int b = d / NN;
  int v = t >> 5, q = t & 31, h = q >> 3;
  int m = cnt[d]; if (m > CAP) m = CAP;

  // ---- phase A: R5 gather verbatim, output -> hgatS (no bias) ----
  for (int base = 0; base < m; base += 32) {
    int i = base + (t >> 2);
    if (i < m) {
      int s = elist[d * CAP + i];
      if ((t & 3) == 0) srcs[li * CAP + i] = s;
      float sc = ssrc[s * HEADS_ + (t & 3)] + sdst[d * HEADS_ + (t & 3)];
      exs[li * 192 + i * 4 + (t & 3)] = __expf(sc);  // shift-invariant
    }
  }
  __syncthreads();
  {
    float den = 1e-16f;
    float4 acc = make_float4(0.f, 0.f, 0.f, 0.f);
    const float* hbase = hbuf + ((size_t)(b * 4 + v) * NN) * DM + q * 4;
    int i = 0;
    for (; i + 4 <= m; i += 4) {
      float ex[4]; unsigned sl[4]; float4 hv[4];
#pragma unroll
      for (int u = 0; u < 4; ++u) {
        ex[u] = exs[li * 192 + (i + u) * 4 + h];
        sl[u] = (unsigned)(srcs[li * CAP + i + u] - b * NN);
        unsigned sls = sl[u] < NN ? sl[u] : 0u;     // clamped always-valid addr
        hv[u] = *(const float4*)(hbase + (size_t)sls * DM);
      }
#pragma unroll
      for (int u = 0; u < 4; ++u) {
        den += ex[u];
        float w = sl[u] < NN ? ex[u] : 0.f;
        acc.x += w * hv[u].x; acc.y += w * hv[u].y;
        acc.z += w * hv[u].z; acc.w += w * hv[u].w;
      }
    }
    for (; i < m; ++i) {
      float ex = exs[li * 192 + i * 4 + h];
      den += ex;
      unsigned sl = (unsigned)(srcs[li * CAP + i] - b * NN);
      if (sl < NN) {
        float4 hv = *(const float4*)(hbase + (size_t)sl * DM);
        acc.x += ex * hv.x; acc.y += ex * hv.y;
        acc.z += ex * hv.z; acc.w += ex * hv.w;
      }
    }
    float r = 1.f / den;
    *(float4*)&hgatS[(li * 4 + v) * 132 + q * 4] =
        make_float4(acc.x * r, acc.y * r, acc.z * r, acc.w * r);
  }
  __syncthreads();

  // ---- phase B: qkvS[8][384] = hgatS @ inw^T + inb ----
  {
    int l = tid & 63, w = tid >> 6;     // lane, wave
    int r = l & 7, cb = l >> 3;         // row, col-base in [0,8)
    float acc[12] = {};
    const float4* I4 = (const float4*)inw;   // [384][32]
    for (int kc = 0; kc < 8; ++kc) {    // K chunks of 16
      __syncthreads();                  // previous chunk consumed
#pragma unroll
      for (int p = 0; p < 6; ++p) {     // stage 1536 float4
        int g = p * 256 + tid;
        int c = g >> 2, kk = g & 3;
        float4 vv = I4[(size_t)c * 32 + kc * 4 + kk];
        *(float4*)&inwS[c * 20 + kk * 4] = vv;
      }
      __syncthreads();
#pragma unroll
      for (int kk = 0; kk < 4; ++kk) {
        float4 a4 = *(const float4*)&hgatS[r * 132 + kc * 16 + kk * 4];
#pragma unroll
        for (int j = 0; j < 12; ++j) {
          float4 b4 = *(const float4*)&inwS[(w * 96 + cb + 8 * j) * 20 + kk * 4];
          acc[j] += a4.x * b4.x + a4.y * b4.y + a4.z * b4.z + a4.w * b4.w;
        }
      }
    }
#pragma unroll
    for (int j = 0; j < 12; ++j) {      // qkvS disjoint from inwS: no barrier
      int c = w * 96 + cb + 8 * j;
      qkvS[r * 392 + c] = acc[j] + inb[c];
    }
  }
  __syncthreads();

  // ---- phase C: register MHA (thread = li,v,q; head = q>>3) ----
  {
    float4 aq = *(const float4*)&qkvS[(li * 4 + v) * 392 + q * 4];
    float S[4];
#pragma unroll
    for (int vk = 0; vk < 4; ++vk) {
      float4 kf = *(const float4*)&qkvS[(li * 4 + vk) * 392 + 128 + q * 4];
      S[vk] = aq.x * kf.x + aq.y * kf.y + aq.z * kf.z + aq.w * kf.w;
    }
#pragma unroll
    for (int vk = 0; vk < 4; ++vk) {    // reduce over head's 8 q-lanes
      float s = S[vk];
      s += __shfl_xor(s, 1);
      s += __shfl_xor(s, 2);
      s += __shfl_xor(s, 4);
      S[vk] = s * 0.17677669529663687f;  // 1/sqrt(32)
    }
    {
      float mx = fmaxf(fmaxf(S[0], S[1]), fmaxf(S[2], S[3]));
      float e0 = __expf(S[0] - mx), e1 = __expf(S[1] - mx);
      float e2 = __expf(S[2] - mx), e3 = __expf(S[3] - mx);
      float inv = 1.f / (e0 + e1 + e2 + e3);
      S[0] = e0 * inv; S[1] = e1 * inv; S[2] = e2 * inv; S[3] = e3 * inv;
    }
    float4 ao = make_float4(0.f, 0.f, 0.f, 0.f);
#pragma unroll
    for (int vk = 0; vk < 4; ++vk) {
      float w = S[vk];
      float4 vf = *(const float4*)&qkvS[(li * 4 + vk) * 392 + 256 + q * 4];
      ao.x += w * vf.x; ao.y += w * vf.y; ao.z += w * vf.z; ao.w += w * vf.w;
    }
    *(float4*)&aoS[li * 512 + v * 128 + q * 4] = ao;
  }
  __syncthreads();

  // ---- phase D: out_proj 8x128, K=128 in 4 staged chunks (R6 structure) ----
  {
    int rr = tid >> 5, oc = tid & 31;
    int li2 = rr >> 2, v2 = rr & 3;
    float occ4[4] = {};
    const float4* O4 = (const float4*)outw;  // [128 col][32]
    for (int kc = 0; kc < 4; ++kc) {
      if (kc) __syncthreads();
#pragma unroll
      for (int p = 0; p < 4; ++p) {     // stage outw chunk (swizzled)
        int g = p * 256 + tid;
        int col = g >> 3, kg = g & 7;
        float4 w4 = O4[(size_t)col * 32 + kc * 8 + kg];
        *(float4*)&outwS[col * 32 + ((kg ^ ((col >> 2) & 7)) << 2)] = w4;
      }
      __syncthreads();
#pragma unroll
      for (int kg = 0; kg < 8; ++kg) {
        float4 af = *(const float4*)&aoS[li2 * 512 + v2 * 128 + kc * 32 + kg * 4];
#pragma unroll
        for (int j = 0; j < 4; ++j) {
          int c = oc * 4 + j;
          float4 w4 = *(const float4*)&outwS[c * 32 + ((kg ^ (oc & 7)) << 2)];
          occ4[j] += af.x * w4.x + af.y * w4.y + af.z * w4.z + af.w * w4.w;
        }
      }
    }
    // epilogue: +outb +bias, remap row (d2, v2) -> (b*4+v)*NN + n
    int d2 = blockIdx.x * 2 + li2;
    int b2 = d2 / NN, n2 = d2 - b2 * NN;
    int om = (b2 * 4 + v2) * NN + n2;
    int nc = oc * 4;
    float4 ob = make_float4(outb[nc] + bias[nc], outb[nc + 1] + bias[nc + 1],
                            outb[nc + 2] + bias[nc + 2], outb[nc + 3] + bias[nc + 3]);
    *(float4*)&out[(size_t)om * DM + nc] =
        make_float4(occ4[0] + ob.x, occ4[1] + ob.y, occ4[2] + ob.z, occ4[3] + ob.w);
  }
}

extern "C" void kernel_launch(void* const* d_in, const int* in_sizes, int n_in,
                              void* d_out, int out_size, void* d_ws, size_t ws_size,
                              hipStream_t stream) {
  const float* x    = (const float*)d_in[0];
  const float* W    = (const float*)d_in[1];
  const float* att  = (const float*)d_in[2];
  const float* inw  = (const float*)d_in[3];
  const float* inb  = (const float*)d_in[4];
  const float* outw = (const float*)d_in[5];
  const float* outb = (const float*)d_in[6];
  const float* bias = (const float*)d_in[7];
  const int*   ei   = (const int*)d_in[8];
  float* out = (float*)d_out;

  float* ws = (float*)d_ws;
  float* hbuf  = ws;                       // 2,048,000  (b,v,n)-major h
  float* ssrc  = ws + 12500000;            // 16,000 } contiguous:
  float* sdst  = ssrc + 16000;             // 16,000 } one 144 KB memset
  int*   cnt   = (int*)(sdst + 16000);     //  4,000 }
  int*   elist = cnt + 4000;               // 192,000 (4000 x CAP)

  // zero ssrc/sdst (rows >=1000 must stay zero) + cnt
  hipMemsetAsync(ssrc, 0, 36000 * sizeof(float), stream);

  k1_kernel<<<500 + EB, 256, 0, stream>>>(x, W, att, hbuf, ssrc, sdst, ei, cnt, elist);
  gfuse2_kernel<<<NTOT / 2, 256, 0, stream>>>(cnt, elist, ssrc, sdst, hbuf,
                                              inw, inb, outw, outb, bias, out);
}

// Round 8
// 138.115 us; speedup vs baseline: 1.2504x; 1.2504x over previous
//
#include <hip/hip_runtime.h>

#define NN 1000
#define HEADS_ 4
#define DM 128
#define EE 64000
#define NTOT 4000
#define ETOT 68000
#define CAP 48     // bucket holds ALL edges per dst: deg ~ Poisson(16)+1, P(>=48) ~ 1e-11
#define EB 34      // edge-builder blocks appended to the h-GEMM dispatch
#define QS 388     // qk row stride (pad +4)

// ---------------------------------------------------------------------------
// 64x64 GEMM tile, K=64: C = A @ Wt^T.  k-group swizzle g = q ^ ((r>>2)&15).
// acc[4][4] only across the staged loop -- proven spill-free (R2/R5, 60 VGPR).
// SCORE: fused GAT score epilogue (rows < 1000 only).
// ---------------------------------------------------------------------------
template <int KK, int SCORE>
__device__ void gemm64(int mi, int ni,
                       const float* __restrict__ A, const float* __restrict__ Wt,
                       float* __restrict__ C, int N,
                       const float* __restrict__ att,
                       float* __restrict__ ssrc, float* __restrict__ sdst) {
  __shared__ float As[64 * 64];
  __shared__ float Bs[64 * 64];
  int tid = threadIdx.x;
  int m0 = mi * 64, n0 = ni * 64;
  int tx = tid & 15, ty = tid >> 4;
  const float4* A4 = (const float4*)A;
  const float4* W4 = (const float4*)Wt;
  float acc[4][4] = {};

  for (int c = 0; c < KK / 64; ++c) {
    __syncthreads();
    {
      int q = tid & 15, r0 = tid >> 4;
#pragma unroll
      for (int p = 0; p < 4; ++p) {  // A: 64 rows
        int r = r0 + p * 16;
        float4 v = A4[(size_t)(m0 + r) * (KK / 4) + c * 16 + q];
        *(float4*)&As[r * 64 + ((q ^ ((r >> 2) & 15)) << 2)] = v;
      }
#pragma unroll
      for (int p = 0; p < 4; ++p) {  // B: 64 rows
        int r = r0 + p * 16;
        float4 v = W4[(size_t)(n0 + r) * (KK / 4) + c * 16 + q];
        *(float4*)&Bs[r * 64 + ((q ^ ((r >> 2) & 15)) << 2)] = v;
      }
    }
    __syncthreads();
#pragma unroll 4
    for (int q = 0; q < 16; ++q) {
      float4 a[4], b[4];
      int sa = (q ^ ty) << 2;
      int sb = (q ^ tx) << 2;
#pragma unroll
      for (int i = 0; i < 4; ++i)
        a[i] = *(const float4*)&As[(ty * 4 + i) * 64 + sa];
#pragma unroll
      for (int j = 0; j < 4; ++j)
        b[j] = *(const float4*)&Bs[(tx * 4 + j) * 64 + sb];
#pragma unroll
      for (int i = 0; i < 4; ++i)
#pragma unroll
        for (int j = 0; j < 4; ++j)
          acc[i][j] += a[i].x * b[j].x + a[i].y * b[j].y
                     + a[i].z * b[j].z + a[i].w * b[j].w;
    }
  }

  int nc = n0 + tx * 4;
#pragma unroll
  for (int i = 0; i < 4; ++i) {
    int m = m0 + ty * 4 + i;
    *(float4*)&C[(size_t)m * N + nc] =
        make_float4(acc[i][0], acc[i][1], acc[i][2], acc[i][3]);
  }

  if (SCORE && m0 < NN) {  // uniform per block
    int hsel = tx >> 3;
    int h = ni * 2 + hsel;
    int kb = (tx & 7) * 4;
    float a0[4], a1[4];
#pragma unroll
    for (int j = 0; j < 4; ++j) {
      a0[j] = att[h * 64 + kb + j];
      a1[j] = att[h * 64 + 32 + kb + j];
    }
#pragma unroll
    for (int i = 0; i < 4; ++i) {
      int m = m0 + ty * 4 + i;
      float p0 = 0.f, p1 = 0.f;
#pragma unroll
      for (int j = 0; j < 4; ++j) {
        float g = acc[i][j];
        float lr = g > 0.f ? g : 0.2f * g;
        p0 += a0[j] * lr;
        p1 += a1[j] * lr;
      }
      p0 += __shfl_xor(p0, 1, 16); p1 += __shfl_xor(p1, 1, 16);
      p0 += __shfl_xor(p0, 2, 16); p1 += __shfl_xor(p1, 2, 16);
      p0 += __shfl_xor(p0, 4, 16); p1 += __shfl_xor(p1, 4, 16);
      if ((tx & 7) == 0 && m < NN) {
        ssrc[m * HEADS_ + h] = p0;
        sdst[m * HEADS_ + h] = p1;
      }
    }
  }
}

// -------- K1: blocks 0..499 = h-GEMM (250 m-tiles x 2 n-tiles) + score
//              blocks 500..499+EB = bucket build    (R5 proven)
__global__ __launch_bounds__(256) void k1_kernel(const float* __restrict__ x,
                                                 const float* __restrict__ W,
                                                 const float* __restrict__ att,
                                                 float* __restrict__ hbuf,
                                                 float* __restrict__ ssrc,
                                                 float* __restrict__ sdst,
                                                 const int* __restrict__ ei,
                                                 int* __restrict__ cnt,
                                                 int* __restrict__ elist) {
  int bid = blockIdx.x;
  if (bid < 500) {
    gemm64<64, 1>(bid >> 1, bid & 1, x, W, hbuf, 128, att, ssrc, sdst);
  } else {
    for (int e = (bid - 500) * 256 + threadIdx.x; e < ETOT; e += EB * 256) {
      int s, d;
      if (e < EE) { s = ei[e]; d = ei[EE + e]; }
      else { s = d = e - EE; }  // self loops
      int pos = atomicAdd(&cnt[d], 1);
      if (pos < CAP) elist[d * CAP + pos] = s;
    }
  }
}

// ---------------------------------------------------------------------------
// K2 (mega): gather(16 nodes -> LDS As) + qkv GEMM + MHA + out_proj.
// 250 blocks x 512 threads, 133,120 B dynamic LDS -> 1 block/CU (2 wv/SIMD,
// same occupancy as R2's 54us fused3-v2, whose phases B-D are verbatim here).
// LDS: As[64][132] (8448 f, persistent, padded: a-reads 2 rows/wave = free)
//      region2 (24832 f), sequential overlays with barriers:
//        A: exs[16][48][4] (3072) + srcs[16][48] int (768)
//        B: Bs[128][64] at +4096 (qkv weight chunks, R2 swizzle)
//        B-epi..C: qk[64][388]
//        C-epi..D: ao[2][64][64] at +0, Bs2[128][64] at +8192 (dead-qk zone)
// ---------------------------------------------------------------------------
__global__ __launch_bounds__(512) void mega_kernel(const int* __restrict__ cnt,
                                                   const int* __restrict__ elist,
                                                   const float* __restrict__ ssrc,
                                                   const float* __restrict__ sdst,
                                                   const float* __restrict__ hbuf,
                                                   const float* __restrict__ inw,
                                                   const float* __restrict__ inb,
                                                   const float* __restrict__ outw,
                                                   const float* __restrict__ outb,
                                                   const float* __restrict__ bias,
                                                   float* __restrict__ out) {
  extern __shared__ float smem[];
  float* As   = smem;                    // [64][132]
  float* rg2  = smem + 8448;             // region2 base
  float* exsF = rg2;                     // [16][48][4]
  int*   srcsI = (int*)(rg2 + 3072);     // [16][48]
  float* Bs   = rg2 + 4096;              // [128][64] (phase B)
  float* qk   = rg2;                     // [64][QS]  (overlay)
  float* ao   = rg2;                     // [2][64][64] (overlay)
  float* Bs2  = rg2 + 8192;              // [128][64] (phase D overlay)

  int tid = threadIdx.x;
  int g0n = blockIdx.x * 16;             // first node of tile

  // ---- phase A1: stage edges + exp(score per head): 32 threads/node ----
  {
    int ln = tid >> 5, t32 = tid & 31;
    int d = g0n + ln;
    int m = cnt[d]; if (m > CAP) m = CAP;
    for (int base = 0; base < m; base += 8) {
      int i = base + (t32 >> 2);
      if (i < m) {
        int s = elist[d * CAP + i];
        if ((t32 & 3) == 0) srcsI[ln * CAP + i] = s;
        float sc = ssrc[s * HEADS_ + (t32 & 3)] + sdst[d * HEADS_ + (t32 & 3)];
        exsF[ln * 192 + i * 4 + (t32 & 3)] = __expf(sc);  // shift-invariant
      }
    }
  }
  __syncthreads();

  // ---- phase A2: gather-aggregate h rows into As (R5-proven math) ----
  {
    int r = tid >> 3, g = tid & 7;       // row in [0,64), f4-group in [0,8)
    int ln = r >> 2, v = r & 3;
    int d = g0n + ln, b = d / NN;
    int m = cnt[d]; if (m > CAP) m = CAP;
    const float* hbase = hbuf + ((size_t)(b * 4 + v) * NN) * DM + g * 4;
    float4 a0 = make_float4(0.f, 0.f, 0.f, 0.f), a1 = a0, a2 = a0, a3 = a0;
    float4 den = make_float4(1e-16f, 1e-16f, 1e-16f, 1e-16f);
    for (int i = 0; i < m; ++i) {
      float4 ex = *(const float4*)&exsF[ln * 192 + i * 4];
      unsigned sl = (unsigned)(srcsI[ln * CAP + i] - b * NN);
      unsigned sc = sl < NN ? sl : 0u;   // clamped always-valid addr
      const float* hrow = hbase + (size_t)sc * DM;
      float4 h0 = *(const float4*)(hrow);        // head 0 cols g*4..
      float4 h1 = *(const float4*)(hrow + 32);   // head 1
      float4 h2 = *(const float4*)(hrow + 64);   // head 2
      float4 h3 = *(const float4*)(hrow + 96);   // head 3
      den.x += ex.x; den.y += ex.y; den.z += ex.z; den.w += ex.w;
      float w0 = sl < NN ? ex.x : 0.f, w1 = sl < NN ? ex.y : 0.f;
      float w2 = sl < NN ? ex.z : 0.f, w3 = sl < NN ? ex.w : 0.f;
      a0.x += w0 * h0.x; a0.y += w0 * h0.y; a0.z += w0 * h0.z; a0.w += w0 * h0.w;
      a1.x += w1 * h1.x; a1.y += w1 * h1.y; a1.z += w1 * h1.z; a1.w += w1 * h1.w;
      a2.x += w2 * h2.x; a2.y += w2 * h2.y; a2.z += w2 * h2.z; a2.w += w2 * h2.w;
      a3.x += w3 * h3.x; a3.y += w3 * h3.y; a3.z += w3 * h3.z; a3.w += w3 * h3.w;
    }
    float i0 = 1.f / den.x, i1 = 1.f / den.y, i2 = 1.f / den.z, i3 = 1.f / den.w;
    *(float4*)&As[r * 132 +       g * 4] = make_float4(a0.x * i0, a0.y * i0, a0.z * i0, a0.w * i0);
    *(float4*)&As[r * 132 +  32 + g * 4] = make_float4(a1.x * i1, a1.y * i1, a1.z * i1, a1.w * i1);
    *(float4*)&As[r * 132 +  64 + g * 4] = make_float4(a2.x * i2, a2.y * i2, a2.z * i2, a2.w * i2);
    *(float4*)&As[r * 132 +  96 + g * 4] = make_float4(a3.x * i3, a3.y * i3, a3.z * i3, a3.w * i3);
  }

  // ---- phase B: qkv GEMM (fused3-v2 verbatim; A from resident padded As) --
  int tx = tid & 31, ty = tid >> 5;
  float acc[3][4][4] = {};
  {
    const float4* W4 = (const float4*)inw;   // [384][32]
#pragma unroll
    for (int c = 0; c < 2; ++c) {
#pragma unroll
      for (int ni = 0; ni < 3; ++ni) {
        __syncthreads();
        {
          int q = tid & 15, r0 = tid >> 4;   // r0 in [0,32)
#pragma unroll
          for (int p = 0; p < 4; ++p) {      // Bs: 128 weight rows
            int r = r0 + p * 32;
            float4 v = W4[(size_t)(ni * 128 + r) * 32 + c * 16 + q];
            *(float4*)&Bs[r * 64 + ((q ^ ((r >> 2) & 15)) << 2)] = v;
          }
        }
        __syncthreads();
#pragma unroll 4
        for (int q = 0; q < 16; ++q) {
          float4 a[4], b[4];
          int sb = (q ^ (tx & 15)) << 2;
#pragma unroll
          for (int i = 0; i < 4; ++i)
            a[i] = *(const float4*)&As[(ty * 4 + i) * 132 + c * 64 + q * 4];
#pragma unroll
          for (int j = 0; j < 4; ++j)
            b[j] = *(const float4*)&Bs[(tx * 4 + j) * 64 + sb];
#pragma unroll
          for (int i = 0; i < 4; ++i)
#pragma unroll
            for (int j = 0; j < 4; ++j)
              acc[ni][i][j] += a[i].x * b[j].x + a[i].y * b[j].y
                             + a[i].z * b[j].z + a[i].w * b[j].w;
        }
      }
    }
  }
  __syncthreads();  // Bs reads done before qk overlay

  // ---- qk epilogue: +inb, write qk rows ----
#pragma unroll
  for (int ni = 0; ni < 3; ++ni) {
    int nc = ni * 128 + tx * 4;
    float4 bb = *(const float4*)&inb[nc];
#pragma unroll
    for (int i = 0; i < 4; ++i) {
      int r = ty * 4 + i;
      *(float4*)&qk[r * QS + nc] =
          make_float4(acc[ni][i][0] + bb.x, acc[ni][i][1] + bb.y,
                      acc[ni][i][2] + bb.z, acc[ni][i][3] + bb.w);
    }
  }
  __syncthreads();

  // ---- phase C: attention (fused3-v2 verbatim) ----
  int ln = tid >> 5;                     // node within tile (== ty)
  int vq2 = (tid >> 3) & 3, h2 = (tid >> 1) & 3, s2 = tid & 1;
  float aww[4];
  {
    const float* qr = &qk[(ln * 4 + vq2) * QS + h2 * 32 + s2 * 16];
    float4 qv[4];
#pragma unroll
    for (int u = 0; u < 4; ++u) qv[u] = *(const float4*)&qr[u * 4];
    float sc[4];
#pragma unroll
    for (int vk = 0; vk < 4; ++vk) {
      const float* kr = &qk[(ln * 4 + vk) * QS + 128 + h2 * 32 + s2 * 16];
      float s = 0.f;
#pragma unroll
      for (int u = 0; u < 4; ++u) {
        float4 kv = *(const float4*)&kr[u * 4];
        s += qv[u].x * kv.x + qv[u].y * kv.y + qv[u].z * kv.z + qv[u].w * kv.w;
      }
      sc[vk] = s;
    }
#pragma unroll
    for (int vk = 0; vk < 4; ++vk)
      sc[vk] = (sc[vk] + __shfl_xor(sc[vk], 1)) * 0.17677669529663687f;
    float mx = fmaxf(fmaxf(sc[0], sc[1]), fmaxf(sc[2], sc[3]));
    float e0 = __expf(sc[0] - mx), e1 = __expf(sc[1] - mx);
    float e2 = __expf(sc[2] - mx), e3 = __expf(sc[3] - mx);
    float inv = 1.f / (e0 + e1 + e2 + e3);
    aww[0] = e0 * inv; aww[1] = e1 * inv; aww[2] = e2 * inv; aww[3] = e3 * inv;
  }

  // ---- ao = aw @ v: read ALL v first, barrier, then overlay-write ----
  float4 o[4];
#pragma unroll
  for (int u = 0; u < 4; ++u) o[u] = make_float4(0.f, 0.f, 0.f, 0.f);
#pragma unroll
  for (int vk = 0; vk < 4; ++vk) {
    const float* vr = &qk[(ln * 4 + vk) * QS + 256 + h2 * 32 + s2 * 16];
    float w = aww[vk];
#pragma unroll
    for (int u = 0; u < 4; ++u) {
      float4 vv = *(const float4*)&vr[u * 4];
      o[u].x += w * vv.x; o[u].y += w * vv.y;
      o[u].z += w * vv.z; o[u].w += w * vv.w;
    }
  }
  __syncthreads();  // all v reads complete before q/k region overwritten
  {
    int r = ln * 4 + vq2;
#pragma unroll
    for (int u = 0; u < 4; ++u) {
      int qp = h2 * 8 + s2 * 4 + u;      // col f4-group in [0,32)
      int cc = qp >> 4, qg = qp & 15;
      *(float4*)&ao[cc * 4096 + r * 64 + ((qg ^ (ln & 15)) << 2)] = o[u];
    }
  }
  __syncthreads();

  // ---- phase D: out_proj 64x128, K=128 (2 chunks via Bs2); remap write ----
  float oc[4][4] = {};
  const float4* O4 = (const float4*)outw;  // [128][32]
#pragma unroll
  for (int c = 0; c < 2; ++c) {
    {
      int q = tid & 15, r0 = tid >> 4;
#pragma unroll
      for (int p = 0; p < 4; ++p) {       // Bs2: 128 outw rows
        int r = r0 + p * 32;
        float4 v = O4[(size_t)r * 32 + c * 16 + q];
        *(float4*)&Bs2[r * 64 + ((q ^ ((r >> 2) & 15)) << 2)] = v;
      }
    }
    __syncthreads();
#pragma unroll 4
    for (int q = 0; q < 16; ++q) {
      float4 a[4], bq[4];
      int sa = (q ^ ty) << 2;
      int sb = (q ^ (tx & 15)) << 2;
#pragma unroll
      for (int i = 0; i < 4; ++i)
        a[i] = *(const float4*)&ao[c * 4096 + (ty * 4 + i) * 64 + sa];
#pragma unroll
      for (int j = 0; j < 4; ++j)
        bq[j] = *(const float4*)&Bs2[(tx * 4 + j) * 64 + sb];
#pragma unroll
      for (int i = 0; i < 4; ++i)
#pragma unroll
        for (int j = 0; j < 4; ++j)
          oc[i][j] += a[i].x * bq[j].x + a[i].y * bq[j].y
                    + a[i].z * bq[j].z + a[i].w * bq[j].w;
    }
    __syncthreads();
  }

  {  // epilogue: +outb +bias, remap row (node,v) -> (b*4+v)*NN + n
    int nc = tx * 4;
    float4 ob = make_float4(outb[nc] + bias[nc], outb[nc + 1] + bias[nc + 1],
                            outb[nc + 2] + bias[nc + 2], outb[nc + 3] + bias[nc + 3]);
#pragma unroll
    for (int i = 0; i < 4; ++i) {
      int r = ty * 4 + i;
      int node = g0n + (r >> 2), vv = r & 3;
      int bg = node / NN, n = node - bg * NN;
      int om = (bg * 4 + vv) * NN + n;
      *(float4*)&out[(size_t)om * DM + nc] =
          make_float4(oc[i][0] + ob.x, oc[i][1] + ob.y,
                      oc[i][2] + ob.z, oc[i][3] + ob.w);
    }
  }
}

extern "C" void kernel_launch(void* const* d_in, const int* in_sizes, int n_in,
                              void* d_out, int out_size, void* d_ws, size_t ws_size,
                              hipStream_t stream) {
  const float* x    = (const float*)d_in[0];
  const float* W    = (const float*)d_in[1];
  const float* att  = (const float*)d_in[2];
  const float* inw  = (const float*)d_in[3];
  const float* inb  = (const float*)d_in[4];
  const float* outw = (const float*)d_in[5];
  const float* outb = (const float*)d_in[6];
  const float* bias = (const float*)d_in[7];
  const int*   ei   = (const int*)d_in[8];
  float* out = (float*)d_out;

  float* ws = (float*)d_ws;
  float* hbuf  = ws;                       // 2,048,000  (b,v,n)-major h
  float* ssrc  = ws + 12500000;            // 16,000 } contiguous:
  float* sdst  = ssrc + 16000;             // 16,000 } one 144 KB memset
  int*   cnt   = (int*)(sdst + 16000);     //  4,000 }
  int*   elist = cnt + 4000;               // 192,000 (4000 x CAP)

  static int lds_opt_in = 0;
  if (!lds_opt_in) {
    hipFuncSetAttribute((const void*)mega_kernel,
                        hipFuncAttributeMaxDynamicSharedMemorySize, 160 * 1024);
    lds_opt_in = 1;
  }

  // zero ssrc/sdst (rows >=1000 must stay zero) + cnt
  hipMemsetAsync(ssrc, 0, 36000 * sizeof(float), stream);

  k1_kernel<<<500 + EB, 256, 0, stream>>>(x, W, att, hbuf, ssrc, sdst, ei, cnt, elist);
  mega_kernel<<<250, 512, 133120, stream>>>(cnt, elist, ssrc, sdst, hbuf,
                                            inw, inb, outw, outb, bias, out);
}